// Round 1
// baseline (458.626 us; speedup 1.0000x reference)
//
#include <hip/hip_runtime.h>
#include <hip/hip_bf16.h>

// ModernNCA fused bf16-MFMA pipeline.
// B=512 queries, N=131072 candidates, D=192, H=256, NY=10.
typedef __bf16 bf16;
typedef __attribute__((ext_vector_type(8))) __bf16 bf16x8;
typedef __attribute__((ext_vector_type(4))) __bf16 bf16x4;
typedef __attribute__((ext_vector_type(4))) float f32x4;

#define NQ    512
#define NC    131072
#define DIM   192
#define HID   256
#define NY    10
#define CHUNK 128
#define NCHUNK (NC / CHUNK)   // 1024

// ---------------- workspace layout (bytes) ----------------
#define OFF_W1T 0u                              // 256x192 bf16 = 98304
#define OFF_W2T (OFF_W1T + 98304u)              // 192x256 bf16 = 98304
#define OFF_XE  (OFF_W2T + 98304u)              // 512x192 bf16 = 196608
#define OFF_X2  (OFF_XE + 196608u)              // 512 f32 = 2048
#define OFF_CE  (OFF_X2 + 2048u)                // 131072x192 bf16 = 50331648
#define OFF_C2  (OFF_CE + 50331648u)            // 131072 f32 = 524288
#define OFF_P   (OFF_C2 + 524288u)              // 512x1024x12 f32 = 25165824
// total = 76,417,024 B

// ---------------- K0: weight transpose+cast ----------------
__global__ __launch_bounds__(256) void k_prep(const float* __restrict__ W1,
                                              const float* __restrict__ W2,
                                              bf16* __restrict__ W1T,
                                              bf16* __restrict__ W2T) {
  int idx = blockIdx.x * 256 + threadIdx.x;   // 0..98303
  if (idx < 192 * 256) {
    int k = idx / 256, n = idx % 256;
    W1T[n * 192 + k] = (bf16)W1[idx];         // W1T[n][k], K-contiguous
  } else {
    int i2 = idx - 192 * 256;
    int k = i2 / 192, n = i2 % 192;
    W2T[n * 256 + k] = (bf16)W2[i2];          // W2T[n][k]
  }
}

// ---------------- K1/K2: encode + residual MLP ----------------
// 64 rows per block, 256 threads (4 waves). Wave owns an n-column slice.
__global__ __launch_bounds__(256) void k_encode(
    const float* __restrict__ xn, const int* __restrict__ xc,
    const float* __restrict__ Wn, const float* __restrict__ bn,
    const float* __restrict__ emb, const float* __restrict__ b1,
    const float* __restrict__ b2, const bf16* __restrict__ W1T,
    const bf16* __restrict__ W2T, bf16* __restrict__ oe,
    float* __restrict__ on2) {
  __shared__ alignas(16) bf16 zt[64][216];   // encoded z (192 cols + pad)
  __shared__ alignas(16) bf16 ht[64][280];   // hidden (256 cols + pad)
  __shared__ float wl[256];                  // W_num(128) | b_num(128)
  __shared__ float n2l[64];

  const int t = threadIdx.x;
  const int row0 = blockIdx.x * 64;
  const int lane = t & 63, w = t >> 6;
  const int l15 = lane & 15, q = lane >> 4;

  wl[t] = (t < 128) ? Wn[t] : bn[t - 128];
  if (t < 64) n2l[t] = 0.f;
  __syncthreads();

  // ---- encode: thread -> (row = t>>2, 48-elem segment = t&3) ----
  {
    int r = t >> 2, sg = t & 3;
    int g = row0 + r;
    float xv[8];
#pragma unroll
    for (int i = 0; i < 8; i++) xv[i] = xn[g * 8 + i];
    int cv[4];
#pragma unroll
    for (int k = 0; k < 4; k++) cv[k] = xc[g * 4 + k];
    int e0 = sg * 48;
    for (int ee = e0; ee < e0 + 48; ee += 8) {
      bf16x8 pack;
#pragma unroll
      for (int u = 0; u < 8; u++) {
        int e = ee + u;
        float v;
        if (e < 128) {
          v = xv[e >> 4] * wl[e] + wl[128 + e];       // num: i*16+j
        } else {
          int k = (e - 128) >> 4, j = e & 15;         // cat: 128+k*16+j
          v = emb[(k * 100 + cv[k]) * 16 + j];
        }
        pack[u] = (bf16)v;
      }
      *(bf16x8*)&zt[r][ee] = pack;
    }
  }
  __syncthreads();

  // ---- GEMM1: H = relu(Z @ W1 + b1); wave w owns cols [w*64, w*64+64) ----
  {
    f32x4 acc[4][4];
    f32x4 z4 = {0.f, 0.f, 0.f, 0.f};
#pragma unroll
    for (int mi = 0; mi < 4; mi++)
#pragma unroll
      for (int ni = 0; ni < 4; ni++) acc[mi][ni] = z4;
#pragma unroll 2
    for (int kk = 0; kk < 192; kk += 32) {
      bf16x8 a[4], b[4];
#pragma unroll
      for (int mi = 0; mi < 4; mi++)
        a[mi] = *(const bf16x8*)&zt[mi * 16 + l15][kk + q * 8];
#pragma unroll
      for (int ni = 0; ni < 4; ni++)
        b[ni] = *(const bf16x8*)&W1T[(size_t)(w * 64 + ni * 16 + l15) * 192 + kk + q * 8];
#pragma unroll
      for (int mi = 0; mi < 4; mi++)
#pragma unroll
        for (int ni = 0; ni < 4; ni++)
          acc[mi][ni] = __builtin_amdgcn_mfma_f32_16x16x32_bf16(a[mi], b[ni], acc[mi][ni], 0, 0, 0);
    }
#pragma unroll
    for (int ni = 0; ni < 4; ni++) {
      int n = w * 64 + ni * 16 + l15;
      float bb = b1[n];
#pragma unroll
      for (int mi = 0; mi < 4; mi++)
#pragma unroll
        for (int r = 0; r < 4; r++) {
          float h = acc[mi][ni][r] + bb;
          ht[mi * 16 + q * 4 + r][n] = (bf16)(h > 0.f ? h : 0.f);
        }
    }
  }
  __syncthreads();

  // ---- GEMM2: out = Z + H @ W2 + b2; wave w owns cols [w*48, w*48+48) ----
  {
    f32x4 acc[4][3];
    f32x4 z4 = {0.f, 0.f, 0.f, 0.f};
#pragma unroll
    for (int mi = 0; mi < 4; mi++)
#pragma unroll
      for (int ni = 0; ni < 3; ni++) acc[mi][ni] = z4;
#pragma unroll 2
    for (int kk = 0; kk < 256; kk += 32) {
      bf16x8 a[4], b[3];
#pragma unroll
      for (int mi = 0; mi < 4; mi++)
        a[mi] = *(const bf16x8*)&ht[mi * 16 + l15][kk + q * 8];
#pragma unroll
      for (int ni = 0; ni < 3; ni++)
        b[ni] = *(const bf16x8*)&W2T[(size_t)(w * 48 + ni * 16 + l15) * 256 + kk + q * 8];
#pragma unroll
      for (int mi = 0; mi < 4; mi++)
#pragma unroll
        for (int ni = 0; ni < 3; ni++)
          acc[mi][ni] = __builtin_amdgcn_mfma_f32_16x16x32_bf16(a[mi], b[ni], acc[mi][ni], 0, 0, 0);
    }
    float nrm[4][4];
#pragma unroll
    for (int mi = 0; mi < 4; mi++)
#pragma unroll
      for (int r = 0; r < 4; r++) nrm[mi][r] = 0.f;
#pragma unroll
    for (int ni = 0; ni < 3; ni++) {
      int n = w * 48 + ni * 16 + l15;
      float bb = b2[n];
#pragma unroll
      for (int mi = 0; mi < 4; mi++)
#pragma unroll
        for (int r = 0; r < 4; r++) {
          int rr = mi * 16 + q * 4 + r;
          float v = (float)zt[rr][n] + acc[mi][ni][r] + bb;
          oe[(size_t)(row0 + rr) * DIM + n] = (bf16)v;
          nrm[mi][r] += v * v;
        }
    }
#pragma unroll
    for (int mi = 0; mi < 4; mi++)
#pragma unroll
      for (int r = 0; r < 4; r++) {
        float s = nrm[mi][r];
        s += __shfl_xor(s, 1);
        s += __shfl_xor(s, 2);
        s += __shfl_xor(s, 4);
        s += __shfl_xor(s, 8);
        if (l15 == 0) atomicAdd(&n2l[mi * 16 + q * 4 + r], s);
      }
  }
  __syncthreads();
  if (t < 64) on2[row0 + t] = n2l[t];
}

// ---------------- K3: flash distance+softmax partials ----------------
// 1024 blocks (one per 128-cand chunk), 512 threads (8 waves).
// Wave w owns cand m-tile w (16 cands) x all 128 queries per query-tile.
__global__ __launch_bounds__(512) void k_dist(
    const bf16* __restrict__ xe, const float* __restrict__ x2v,
    const bf16* __restrict__ ce, const float* __restrict__ c2v,
    const float* __restrict__ cy, float* __restrict__ P) {
  __shared__ alignas(16) bf16 ct[128][216];   // chunk encodings
  __shared__ alignas(16) bf16 ET[128][152];   // exp tile: [query][cand]
  __shared__ float mpart[8][128];
  __shared__ float lpart[8][128];
  __shared__ float mfin[128];

  const int t = threadIdx.x;
  const int n0 = blockIdx.x * CHUNK;
  const int lane = t & 63, w = t >> 6;        // w = wave 0..7
  const int l15 = lane & 15, q = lane >> 4;

  // stage ce chunk -> ct (192 bf16 per row; 4 threads per row, 6 uint4 each)
  {
    int r = t >> 2, qu = t & 3;
    const uint4* src = (const uint4*)(ce + (size_t)(n0 + r) * DIM);
    uint4* dst = (uint4*)(&ct[r][0]);
#pragma unroll
    for (int i = 0; i < 6; i++) dst[qu * 6 + i] = src[qu * 6 + i];
  }

  // Y B-fragments in registers: lane holds Y[kb*32 + q*8 + jj][l15] (l15>=10 -> 0)
  bf16x8 yf[4];
#pragma unroll
  for (int kb = 0; kb < 4; kb++) {
#pragma unroll
    for (int jj = 0; jj < 8; jj++) {
      int cand = n0 + kb * 32 + q * 8 + jj;
      float v = (l15 < 10) ? cy[(size_t)cand * NY + l15] : 0.f;
      yf[kb][jj] = (bf16)v;
    }
  }
  // candidate norms for this lane's rows (fixed across query tiles)
  float c2r[4];
#pragma unroll
  for (int r = 0; r < 4; r++) c2r[r] = c2v[n0 + w * 16 + q * 4 + r];

  __syncthreads();

  for (int qt = 0; qt < 4; qt++) {
    const int q0 = qt * 128;
    f32x4 acc[8];
    f32x4 z4 = {0.f, 0.f, 0.f, 0.f};
#pragma unroll
    for (int nj = 0; nj < 8; nj++) acc[nj] = z4;

    // dist GEMM: D[cand][query] = c . x   (A = ct rows, B = xe rows as B^T)
#pragma unroll 3
    for (int kk = 0; kk < 192; kk += 32) {
      bf16x8 a = *(const bf16x8*)&ct[w * 16 + l15][kk + q * 8];
      bf16x8 b[8];
#pragma unroll
      for (int nj = 0; nj < 8; nj++)
        b[nj] = *(const bf16x8*)&xe[(size_t)(q0 + nj * 16 + l15) * DIM + kk + q * 8];
#pragma unroll
      for (int nj = 0; nj < 8; nj++)
        acc[nj] = __builtin_amdgcn_mfma_f32_16x16x32_bf16(a, b[nj], acc[nj], 0, 0, 0);
    }

    // epilogue: s = -dist
    float x2l[8];
#pragma unroll
    for (int nj = 0; nj < 8; nj++) x2l[nj] = x2v[q0 + nj * 16 + l15];
#pragma unroll
    for (int nj = 0; nj < 8; nj++)
#pragma unroll
      for (int r = 0; r < 4; r++) {
        float d2 = x2l[nj] + c2r[r] - 2.f * acc[nj][r];
        acc[nj][r] = -sqrtf(fmaxf(d2, 0.f));
      }

    // wave-partial max per query (in-reg over 4 cands, shfl over q-groups)
#pragma unroll
    for (int nj = 0; nj < 8; nj++) {
      float m = acc[nj][0];
#pragma unroll
      for (int r = 1; r < 4; r++) m = fmaxf(m, acc[nj][r]);
      m = fmaxf(m, __shfl_xor(m, 16));
      m = fmaxf(m, __shfl_xor(m, 32));
      if (q == 0) mpart[w][nj * 16 + l15] = m;
    }
    __syncthreads();
    if (t < 128) {
      float m = mpart[0][t];
#pragma unroll
      for (int i = 1; i < 8; i++) m = fmaxf(m, mpart[i][t]);
      mfin[t] = m;
    }
    __syncthreads();

    // exp, write E tile (A-frag layout), wave-partial l
#pragma unroll
    for (int nj = 0; nj < 8; nj++) {
      float mf = mfin[nj * 16 + l15];
      float l = 0.f;
      bf16x4 ev;
#pragma unroll
      for (int r = 0; r < 4; r++) {
        float e = __expf(acc[nj][r] - mf);
        l += e;
        ev[r] = (bf16)e;
      }
      *(bf16x4*)&ET[nj * 16 + l15][w * 16 + q * 4] = ev;
      l += __shfl_xor(l, 16);
      l += __shfl_xor(l, 32);
      if (q == 0) lpart[w][nj * 16 + l15] = l;
    }
    __syncthreads();

    // O = E(128q x 128c) @ Y(128c x 16) — wave w owns query m-tile w
    f32x4 oacc = z4;
#pragma unroll
    for (int kb = 0; kb < 4; kb++) {
      bf16x8 a = *(const bf16x8*)&ET[w * 16 + l15][kb * 32 + q * 8];
      oacc = __builtin_amdgcn_mfma_f32_16x16x32_bf16(a, yf[kb], oacc, 0, 0, 0);
    }
    // write partials: P[query][chunk][12] = {m, l, o[10]}
    if (t < 128) {
      float l8 = lpart[0][t];
#pragma unroll
      for (int i = 1; i < 8; i++) l8 += lpart[i][t];
      float* p = &P[((size_t)(q0 + t) * NCHUNK + blockIdx.x) * 12];
      p[0] = mfin[t];
      p[1] = l8;
    }
    if (l15 < 10) {
#pragma unroll
      for (int r = 0; r < 4; r++) {
        int Q = w * 16 + q * 4 + r;
        P[((size_t)(q0 + Q) * NCHUNK + blockIdx.x) * 12 + 2 + l15] = oacc[r];
      }
    }
    __syncthreads();
  }
}

// ---------------- K4: combine partials ----------------
__global__ __launch_bounds__(256) void k_comb(const float* __restrict__ P,
                                              float* __restrict__ out) {
  __shared__ float red[4][11];
  __shared__ float mred[4];
  __shared__ float mfs;
  const int t = threadIdx.x;
  const int qy = blockIdx.x;
  const int lane = t & 63, w = t >> 6;

  float pm[4], pl[4], po[4][10];
#pragma unroll
  for (int i = 0; i < 4; i++) {
    int ch = t + 256 * i;
    const float* p = &P[((size_t)qy * NCHUNK + ch) * 12];
    pm[i] = p[0];
    pl[i] = p[1];
#pragma unroll
    for (int j = 0; j < 10; j++) po[i][j] = p[2 + j];
  }
  float m = fmaxf(fmaxf(pm[0], pm[1]), fmaxf(pm[2], pm[3]));
#pragma unroll
  for (int d = 1; d < 64; d <<= 1) m = fmaxf(m, __shfl_xor(m, d));
  if (lane == 0) mred[w] = m;
  __syncthreads();
  if (t == 0) mfs = fmaxf(fmaxf(mred[0], mred[1]), fmaxf(mred[2], mred[3]));
  __syncthreads();
  float M = mfs;

  float l = 0.f, o[10];
#pragma unroll
  for (int j = 0; j < 10; j++) o[j] = 0.f;
#pragma unroll
  for (int i = 0; i < 4; i++) {
    float sc = __expf(pm[i] - M);
    l += pl[i] * sc;
#pragma unroll
    for (int j = 0; j < 10; j++) o[j] += po[i][j] * sc;
  }
#pragma unroll
  for (int d = 1; d < 64; d <<= 1) {
    l += __shfl_xor(l, d);
#pragma unroll
    for (int j = 0; j < 10; j++) o[j] += __shfl_xor(o[j], d);
  }
  if (lane == 0) {
    red[w][0] = l;
#pragma unroll
    for (int j = 0; j < 10; j++) red[w][1 + j] = o[j];
  }
  __syncthreads();
  if (t < 10) {
    float oo = red[0][1 + t] + red[1][1 + t] + red[2][1 + t] + red[3][1 + t];
    float ll = red[0][0] + red[1][0] + red[2][0] + red[3][0];
    out[qy * NY + t] = oo / ll;
  }
}

// ---------------- launcher ----------------
extern "C" void kernel_launch(void* const* d_in, const int* in_sizes, int n_in,
                              void* d_out, int out_size, void* d_ws, size_t ws_size,
                              hipStream_t stream) {
  (void)in_sizes; (void)n_in; (void)out_size; (void)ws_size;
  const float* x_num = (const float*)d_in[0];
  const int*   x_cat = (const int*)d_in[1];
  const float* c_num = (const float*)d_in[2];
  const int*   c_cat = (const int*)d_in[3];
  const float* c_y   = (const float*)d_in[4];
  const float* W_num = (const float*)d_in[5];
  const float* b_num = (const float*)d_in[6];
  const float* emb   = (const float*)d_in[7];
  const float* W1    = (const float*)d_in[8];
  const float* b1    = (const float*)d_in[9];
  const float* W2    = (const float*)d_in[10];
  const float* b2    = (const float*)d_in[11];
  float* out = (float*)d_out;

  char* ws = (char*)d_ws;
  bf16*  W1T = (bf16*)(ws + OFF_W1T);
  bf16*  W2T = (bf16*)(ws + OFF_W2T);
  bf16*  xe  = (bf16*)(ws + OFF_XE);
  float* x2v = (float*)(ws + OFF_X2);
  bf16*  ce  = (bf16*)(ws + OFF_CE);
  float* c2v = (float*)(ws + OFF_C2);
  float* P   = (float*)(ws + OFF_P);

  k_prep<<<dim3(384), dim3(256), 0, stream>>>(W1, W2, W1T, W2T);
  k_encode<<<dim3(NQ / 64), dim3(256), 0, stream>>>(
      x_num, x_cat, W_num, b_num, emb, b1, b2, W1T, W2T, xe, x2v);
  k_encode<<<dim3(NC / 64), dim3(256), 0, stream>>>(
      c_num, c_cat, W_num, b_num, emb, b1, b2, W1T, W2T, ce, c2v);
  k_dist<<<dim3(NCHUNK), dim3(512), 0, stream>>>(xe, x2v, ce, c2v, c_y, P);
  k_comb<<<dim3(NQ), dim3(256), 0, stream>>>(P, out);
}

// Round 2
// 321.613 us; speedup vs baseline: 1.4260x; 1.4260x over previous
//
#include <hip/hip_runtime.h>
#include <hip/hip_bf16.h>

// ModernNCA fused bf16-MFMA pipeline, v2.
// B=512 queries, N=131072 candidates, D=192, H=256, NY=10.
// Key insight: dist ~ O(3) so softmax needs NO max subtraction -> partials
// combine by pure summation; l folds into the PV MFMA as a ones-column.
typedef __bf16 bf16;
typedef __attribute__((ext_vector_type(8))) __bf16 bf16x8;
typedef __attribute__((ext_vector_type(4))) __bf16 bf16x4;
typedef __attribute__((ext_vector_type(4))) float f32x4;

#define NQ     512
#define NC     131072
#define DIM    192
#define NY     10
#define NSLICE 1024          // k_dist blocks; 128 cands each (2 chunks of 64)

// ---------------- workspace layout (bytes) ----------------
#define OFF_W1T 0u                              // 256x192 bf16 = 98304
#define OFF_W2T (OFF_W1T + 98304u)              // 192x256 bf16 = 98304
#define OFF_XE  (OFF_W2T + 98304u)              // 512x192 bf16 = 196608
#define OFF_X2  (OFF_XE + 196608u)              // 512 f32 = 2048
#define OFF_CE  (OFF_X2 + 2048u)                // 131072x192 bf16 = 50331648
#define OFF_C2  (OFF_CE + 50331648u)            // 131072 f32 = 524288
#define OFF_P   (OFF_C2 + 524288u)              // 512x1024x12 f32 = 25165824
// total = 76,417,024 B

// ---------------- K0: weight transpose+cast ----------------
__global__ __launch_bounds__(256) void k_prep(const float* __restrict__ W1,
                                              const float* __restrict__ W2,
                                              bf16* __restrict__ W1T,
                                              bf16* __restrict__ W2T) {
  int idx = blockIdx.x * 256 + threadIdx.x;   // 0..98303
  if (idx < 192 * 256) {
    int k = idx / 256, n = idx % 256;
    W1T[n * 192 + k] = (bf16)W1[idx];         // W1T[n][k], K-contiguous
  } else {
    int i2 = idx - 192 * 256;
    int k = i2 / 192, n = i2 % 192;
    W2T[n * 256 + k] = (bf16)W2[i2];          // W2T[n][k]
  }
}

// ---------------- K1/K2: encode + residual MLP ----------------
// 64 rows per block, 256 threads (4 waves). Wave owns an n-column slice.
__global__ __launch_bounds__(256, 2) void k_encode(
    const float* __restrict__ xn, const int* __restrict__ xc,
    const float* __restrict__ Wn, const float* __restrict__ bn,
    const float* __restrict__ emb, const float* __restrict__ b1,
    const float* __restrict__ b2, const bf16* __restrict__ W1T,
    const bf16* __restrict__ W2T, bf16* __restrict__ oe,
    float* __restrict__ on2) {
  __shared__ alignas(16) bf16 zt[64][200];   // encoded z (192 cols + pad)
  __shared__ alignas(16) bf16 ht[64][264];   // hidden (256 cols + pad); reused as ot
  __shared__ float n2l[64];

  const int t = threadIdx.x;
  const int row0 = blockIdx.x * 64;
  const int lane = t & 63, w = t >> 6;
  const int l15 = lane & 15, q = lane >> 4;

  if (t < 64) n2l[t] = 0.f;

  // ---- encode: thread -> (row = t>>2, 48-elem segment = t&3) ----
  {
    int r = t >> 2, sg = t & 3;
    int g = row0 + r;
    float xv[8];
#pragma unroll
    for (int i = 0; i < 8; i++) xv[i] = xn[g * 8 + i];
    int cv[4];
#pragma unroll
    for (int k = 0; k < 4; k++) cv[k] = xc[g * 4 + k];
    int e0 = sg * 48;
    for (int ee = e0; ee < e0 + 48; ee += 8) {
      bf16x8 pack;
#pragma unroll
      for (int u = 0; u < 8; u++) {
        int e = ee + u;
        float v;
        if (e < 128) {
          v = xv[e >> 4] * Wn[e] + bn[e];             // num: i*16+j
        } else {
          int k = (e - 128) >> 4, j = e & 15;         // cat: 128+k*16+j
          v = emb[(k * 100 + cv[k]) * 16 + j];
        }
        pack[u] = (bf16)v;
      }
      *(bf16x8*)&zt[r][ee] = pack;
    }
  }
  __syncthreads();

  // ---- GEMM1: H = relu(Z @ W1 + b1); wave w owns cols [w*64, w*64+64) ----
  {
    f32x4 acc[4][4];
    f32x4 z4 = {0.f, 0.f, 0.f, 0.f};
#pragma unroll
    for (int mi = 0; mi < 4; mi++)
#pragma unroll
      for (int ni = 0; ni < 4; ni++) acc[mi][ni] = z4;
#pragma unroll 2
    for (int kk = 0; kk < 192; kk += 32) {
      bf16x8 a[4], b[4];
#pragma unroll
      for (int mi = 0; mi < 4; mi++)
        a[mi] = *(const bf16x8*)&zt[mi * 16 + l15][kk + q * 8];
#pragma unroll
      for (int ni = 0; ni < 4; ni++)
        b[ni] = *(const bf16x8*)&W1T[(size_t)(w * 64 + ni * 16 + l15) * 192 + kk + q * 8];
#pragma unroll
      for (int mi = 0; mi < 4; mi++)
#pragma unroll
        for (int ni = 0; ni < 4; ni++)
          acc[mi][ni] = __builtin_amdgcn_mfma_f32_16x16x32_bf16(a[mi], b[ni], acc[mi][ni], 0, 0, 0);
    }
#pragma unroll
    for (int ni = 0; ni < 4; ni++) {
      int n = w * 64 + ni * 16 + l15;
      float bb = b1[n];
#pragma unroll
      for (int mi = 0; mi < 4; mi++)
#pragma unroll
        for (int r = 0; r < 4; r++) {
          float h = acc[mi][ni][r] + bb;
          ht[mi * 16 + q * 4 + r][n] = (bf16)(h > 0.f ? h : 0.f);
        }
    }
  }
  __syncthreads();

  // ---- GEMM2 k-loop: acc = H @ W2; wave w owns cols [w*48, w*48+48) ----
  f32x4 acc2[4][3];
  {
    f32x4 z4 = {0.f, 0.f, 0.f, 0.f};
#pragma unroll
    for (int mi = 0; mi < 4; mi++)
#pragma unroll
      for (int ni = 0; ni < 3; ni++) acc2[mi][ni] = z4;
#pragma unroll 2
    for (int kk = 0; kk < 256; kk += 32) {
      bf16x8 a[4], b[3];
#pragma unroll
      for (int mi = 0; mi < 4; mi++)
        a[mi] = *(const bf16x8*)&ht[mi * 16 + l15][kk + q * 8];
#pragma unroll
      for (int ni = 0; ni < 3; ni++)
        b[ni] = *(const bf16x8*)&W2T[(size_t)(w * 48 + ni * 16 + l15) * 256 + kk + q * 8];
#pragma unroll
      for (int mi = 0; mi < 4; mi++)
#pragma unroll
        for (int ni = 0; ni < 3; ni++)
          acc2[mi][ni] = __builtin_amdgcn_mfma_f32_16x16x32_bf16(a[mi], b[ni], acc2[mi][ni], 0, 0, 0);
    }
  }
  __syncthreads();   // all ht A-frag reads done; safe to reuse ht as ot

  // ---- epilogue: v = z + acc2 + b2 -> ot (stride 196, conflict-free), norms ----
  bf16* ot = &ht[0][0];   // flat, stride 196 (fits: 64*196 <= 64*264)
  {
    float nrm[4][4];
#pragma unroll
    for (int mi = 0; mi < 4; mi++)
#pragma unroll
      for (int r = 0; r < 4; r++) nrm[mi][r] = 0.f;
#pragma unroll
    for (int ni = 0; ni < 3; ni++) {
      int n = w * 48 + ni * 16 + l15;
      float bb = b2[n];
#pragma unroll
      for (int mi = 0; mi < 4; mi++)
#pragma unroll
        for (int r = 0; r < 4; r++) {
          int rr = mi * 16 + q * 4 + r;
          float v = (float)zt[rr][n] + acc2[mi][ni][r] + bb;
          ot[rr * 196 + n] = (bf16)v;
          nrm[mi][r] += v * v;
        }
    }
#pragma unroll
    for (int mi = 0; mi < 4; mi++)
#pragma unroll
      for (int r = 0; r < 4; r++) {
        float s = nrm[mi][r];
        s += __shfl_xor(s, 1);
        s += __shfl_xor(s, 2);
        s += __shfl_xor(s, 4);
        s += __shfl_xor(s, 8);
        if (l15 == 0) atomicAdd(&n2l[mi * 16 + q * 4 + r], s);
      }
  }
  __syncthreads();

  // ---- coalesced copy-out: ot(stride 196) -> oe(stride 192), 8B granules ----
  {
    uint2* dst = (uint2*)(oe + (size_t)row0 * DIM);   // 48 uint2 per row
#pragma unroll
    for (int j = t; j < 64 * 48; j += 256) {
      int r = j / 48, cc = j - r * 48;
      dst[r * 48 + cc] = *(const uint2*)&ot[r * 196 + cc * 4];
    }
  }
  if (t < 64) on2[row0 + t] = n2l[t];
}

// ---------------- K3: dist + exp + PV, no-max flash ----------------
// 1024 blocks x 256 thr (4 waves). Block owns 128 cands (2 chunks of 64).
// Wave owns 32 queries per query-tile; ET is wave-private -> no barriers
// inside the qt loop. O/l accumulate across chunks in registers.
__global__ __launch_bounds__(256, 3) void k_dist(
    const bf16* __restrict__ xe, const float* __restrict__ x2v,
    const bf16* __restrict__ ce, const float* __restrict__ c2v,
    const float* __restrict__ cy, float* __restrict__ P) {
  __shared__ alignas(16) bf16 ct[64][200];     // chunk encodings (25.6 KB)
  __shared__ alignas(16) bf16 ET[4][32][72];   // per-wave exp tiles (18.4 KB)

  const int t = threadIdx.x;
  const int n0 = blockIdx.x * 128;
  const int lane = t & 63, w = t >> 6;
  const int l15 = lane & 15, q = lane >> 4;

  f32x4 z4 = {0.f, 0.f, 0.f, 0.f};
  f32x4 oacc[4][2];
#pragma unroll
  for (int qt = 0; qt < 4; qt++)
#pragma unroll
    for (int mi = 0; mi < 2; mi++) oacc[qt][mi] = z4;

  for (int c = 0; c < 2; ++c) {
    if (c) __syncthreads();                    // prior chunk's ct reads done
    {
      int r = t >> 2, qu = t & 3;
      const uint4* src = (const uint4*)(ce + (size_t)(n0 + c * 64 + r) * DIM);
      uint4* dst = (uint4*)&ct[r][0];
#pragma unroll
      for (int i = 0; i < 6; i++) dst[qu * 6 + i] = src[qu * 6 + i];
    }
    __syncthreads();

    // per-chunk constants: candidate norms + Y B-frags (col 10 = ones -> l)
    f32x4 c2r[4];
#pragma unroll
    for (int mc = 0; mc < 4; mc++)
      c2r[mc] = *(const f32x4*)&c2v[n0 + c * 64 + mc * 16 + q * 4];
    bf16x8 yf[2];
#pragma unroll
    for (int kb = 0; kb < 2; kb++)
#pragma unroll
      for (int jj = 0; jj < 8; jj++) {
        int cand = n0 + c * 64 + kb * 32 + q * 8 + jj;
        float v = (l15 < 10) ? cy[(size_t)cand * NY + l15]
                             : (l15 == 10 ? 1.f : 0.f);
        yf[kb][jj] = (bf16)v;
      }

    for (int qt = 0; qt < 4; ++qt) {
      const int qbase = qt * 128 + w * 32;
      f32x4 acc[4][2];
#pragma unroll
      for (int mc = 0; mc < 4; mc++)
#pragma unroll
        for (int nq = 0; nq < 2; nq++) acc[mc][nq] = z4;

      // dist GEMM: D[cand][query]; A = ct (LDS), B = xe rows (global, L2-hot)
#pragma unroll 2
      for (int kk = 0; kk < 192; kk += 32) {
        bf16x8 a[4], b[2];
#pragma unroll
        for (int mc = 0; mc < 4; mc++)
          a[mc] = *(const bf16x8*)&ct[mc * 16 + l15][kk + q * 8];
#pragma unroll
        for (int nq = 0; nq < 2; nq++)
          b[nq] = *(const bf16x8*)&xe[(size_t)(qbase + nq * 16 + l15) * DIM + kk + q * 8];
#pragma unroll
        for (int mc = 0; mc < 4; mc++)
#pragma unroll
          for (int nq = 0; nq < 2; nq++)
            acc[mc][nq] = __builtin_amdgcn_mfma_f32_16x16x32_bf16(a[mc], b[nq], acc[mc][nq], 0, 0, 0);
      }

      // epilogue: e = exp(-sqrt(d2)); write wave-private ET (A-frag layout)
      float x2l[2];
#pragma unroll
      for (int nq = 0; nq < 2; nq++) x2l[nq] = x2v[qbase + nq * 16 + l15];
#pragma unroll
      for (int nq = 0; nq < 2; nq++)
#pragma unroll
        for (int mc = 0; mc < 4; mc++) {
          bf16x4 ev;
#pragma unroll
          for (int r = 0; r < 4; r++) {
            float d2 = x2l[nq] + c2r[mc][r] - 2.f * acc[mc][nq][r];
            ev[r] = (bf16)__expf(-sqrtf(fmaxf(d2, 0.f)));
          }
          *(bf16x4*)&ET[w][nq * 16 + l15][mc * 16 + q * 4] = ev;
        }

      // PV: O[32q x 16] += E(32q x 64c) @ Y(64c x 16) — wave-private, no barrier
#pragma unroll
      for (int mi = 0; mi < 2; mi++)
#pragma unroll
        for (int kb = 0; kb < 2; kb++) {
          bf16x8 a = *(const bf16x8*)&ET[w][mi * 16 + l15][kb * 32 + q * 8];
          oacc[qt][mi] = __builtin_amdgcn_mfma_f32_16x16x32_bf16(a, yf[kb], oacc[qt][mi], 0, 0, 0);
        }
    }
  }

  // write partials: P[query][slice][12] = {o[10], l, pad}
  if (l15 < 11) {
#pragma unroll
    for (int qt = 0; qt < 4; qt++)
#pragma unroll
      for (int mi = 0; mi < 2; mi++)
#pragma unroll
        for (int r = 0; r < 4; r++) {
          int query = qt * 128 + w * 32 + mi * 16 + q * 4 + r;
          P[((size_t)query * NSLICE + blockIdx.x) * 12 + l15] = oacc[qt][mi][r];
        }
  }
}

// ---------------- K4: combine (pure sum — no max needed) ----------------
__global__ __launch_bounds__(256) void k_comb(const float* __restrict__ P,
                                              float* __restrict__ out) {
  __shared__ float red[4][11];
  const int t = threadIdx.x;
  const int qy = blockIdx.x;
  const int lane = t & 63, w = t >> 6;

  float s[11];
#pragma unroll
  for (int j = 0; j < 11; j++) s[j] = 0.f;
#pragma unroll
  for (int i = 0; i < 4; i++) {
    const float* p = &P[((size_t)qy * NSLICE + t + 256 * i) * 12];
    f32x4 v0 = *(const f32x4*)&p[0];
    f32x4 v1 = *(const f32x4*)&p[4];
    f32x4 v2 = *(const f32x4*)&p[8];
#pragma unroll
    for (int j = 0; j < 4; j++) s[j] += v0[j];
#pragma unroll
    for (int j = 0; j < 4; j++) s[4 + j] += v1[j];
#pragma unroll
    for (int j = 0; j < 3; j++) s[8 + j] += v2[j];   // p[11] is pad — skip
  }
#pragma unroll
  for (int d = 1; d < 64; d <<= 1)
#pragma unroll
    for (int j = 0; j < 11; j++) s[j] += __shfl_xor(s[j], d);
  if (lane == 0)
#pragma unroll
    for (int j = 0; j < 11; j++) red[w][j] = s[j];
  __syncthreads();
  if (t < 10) {
    float o = red[0][t] + red[1][t] + red[2][t] + red[3][t];
    float l = red[0][10] + red[1][10] + red[2][10] + red[3][10];
    out[qy * NY + t] = o / l;
  }
}

// ---------------- launcher ----------------
extern "C" void kernel_launch(void* const* d_in, const int* in_sizes, int n_in,
                              void* d_out, int out_size, void* d_ws, size_t ws_size,
                              hipStream_t stream) {
  (void)in_sizes; (void)n_in; (void)out_size; (void)ws_size;
  const float* x_num = (const float*)d_in[0];
  const int*   x_cat = (const int*)d_in[1];
  const float* c_num = (const float*)d_in[2];
  const int*   c_cat = (const int*)d_in[3];
  const float* c_y   = (const float*)d_in[4];
  const float* W_num = (const float*)d_in[5];
  const float* b_num = (const float*)d_in[6];
  const float* emb   = (const float*)d_in[7];
  const float* W1    = (const float*)d_in[8];
  const float* b1    = (const float*)d_in[9];
  const float* W2    = (const float*)d_in[10];
  const float* b2    = (const float*)d_in[11];
  float* out = (float*)d_out;

  char* ws = (char*)d_ws;
  bf16*  W1T = (bf16*)(ws + OFF_W1T);
  bf16*  W2T = (bf16*)(ws + OFF_W2T);
  bf16*  xe  = (bf16*)(ws + OFF_XE);
  float* x2v = (float*)(ws + OFF_X2);
  bf16*  ce  = (bf16*)(ws + OFF_CE);
  float* c2v = (float*)(ws + OFF_C2);
  float* P   = (float*)(ws + OFF_P);

  k_prep<<<dim3(384), dim3(256), 0, stream>>>(W1, W2, W1T, W2T);
  k_encode<<<dim3(NQ / 64), dim3(256), 0, stream>>>(
      x_num, x_cat, W_num, b_num, emb, b1, b2, W1T, W2T, xe, x2v);
  k_encode<<<dim3(NC / 64), dim3(256), 0, stream>>>(
      c_num, c_cat, W_num, b_num, emb, b1, b2, W1T, W2T, ce, c2v);
  k_dist<<<dim3(NSLICE), dim3(256), 0, stream>>>(xe, x2v, ce, c2v, c_y, P);
  k_comb<<<dim3(NQ), dim3(256), 0, stream>>>(P, out);
}